// Round 10
// baseline (177.715 us; speedup 1.0000x reference)
//
#include <hip/hip_runtime.h>
#include <cstdint>
#include <cstddef>

#define NG 3
#define NB 32
#define NT 1024
#define ND 512
#define NU 512

typedef __bf16 bf16x8 __attribute__((ext_vector_type(8)));
typedef float  f32x16 __attribute__((ext_vector_type(16)));

static __device__ __forceinline__ unsigned int f2bf(float f) {
    union { float f; unsigned int u; } v; v.f = f;
    return (v.u + 0x7FFFu + ((v.u >> 16) & 1u)) >> 16;   // RNE f32->bf16
}

// packed RNE f32x2 -> bf16x2 in one instruction
static __device__ __forceinline__ unsigned int cvt_pk_bf16(float lo, float hi) {
    unsigned int r;
    asm("v_cvt_pk_bf16_f32 %0, %1, %2" : "=v"(r) : "v"(lo), "v"(hi));
    return r;
}

static __device__ __forceinline__ bf16x8 ld_bf16x8(const char* base, int off) {
    return __builtin_bit_cast(bf16x8, *(const uint4*)(base + off));
}

#define AS1(p) ((const __attribute__((address_space(1))) void*)(p))
#define AS3(p) ((__attribute__((address_space(3))) void*)(p))

// ---------- kernel 1: qb[g,b,u] = sum_d query[g,b,d]*W1[g,d,u] + b1 + b2 ----------
__global__ __launch_bounds__(256) void prep_qb_kernel(
    const float* __restrict__ query, const float* __restrict__ W1,
    const float* __restrict__ b1, const float* __restrict__ b2,
    float* __restrict__ qb)
{
    __shared__ float qs[NB][ND];                    // 64 KiB
    const int g  = blockIdx.x >> 3;
    const int uc = blockIdx.x & 7;
    const int tid = threadIdx.x;

    const float4* qsrc = (const float4*)(query + (size_t)g * NB * ND);
    #pragma unroll
    for (int i = 0; i < 16; ++i)
        ((float4*)&qs[0][0])[tid + i * 256] = qsrc[tid + i * 256];
    __syncthreads();

    const int u  = uc * 64 + (tid & 63);
    const int b0 = tid >> 6;                        // 0..3
    float acc[8] = {};
    const float* w1col = W1 + (size_t)g * ND * NU + u;
    for (int d = 0; d < ND; ++d) {
        float w = w1col[(size_t)d * NU];            // coalesced over u
        #pragma unroll
        for (int j = 0; j < 8; ++j)
            acc[j] = fmaf(qs[b0 + 4 * j][d], w, acc[j]);  // LDS broadcast
    }
    const float bias = b1[g * NU + u] + b2[g * NU + u];
    #pragma unroll
    for (int j = 0; j < 8; ++j)
        qb[((size_t)g * NB + (b0 + 4 * j)) * NU + u] = acc[j] + bias;
}

// ---------- kernel 2: w2t = DMA-ready swizzled bf16 image of W2^T ----------
// Chunks of 32 KiB keyed by (g, nb=u>>8, ks=d>>6): 256 u-rows x 64 k, row
// stride 128 B, byte-in-row = (k'*2) ^ ((u'&7)<<4). Linear global_load_lds.
__global__ __launch_bounds__(256) void prep_w2t_kernel(
    const float* __restrict__ W2, char* __restrict__ w2t)
{
    __shared__ float tile[64][65];                  // +1 pad: conflict-free transpose
    const int g  = blockIdx.x >> 6;
    const int tb = blockIdx.x & 63;
    const int d0 = (tb >> 3) * 64;
    const int u0 = (tb & 7) * 64;
    const int tx = threadIdx.x & 63;
    const int ty = threadIdx.x >> 6;

    const float* src = W2 + (size_t)g * ND * NU;
    #pragma unroll
    for (int k = 0; k < 16; ++k) {
        int r = ty + 4 * k;
        tile[r][tx] = src[(size_t)(d0 + r) * NU + (u0 + tx)];   // tile[d_loc][u_loc]
    }
    __syncthreads();
    #pragma unroll
    for (int k = 0; k < 16; ++k) {
        int ul = ty + 4 * k;
        int u  = u0 + ul;
        int d  = d0 + tx;
        unsigned short h = (unsigned short)f2bf(tile[tx][ul]);  // = W2[d][u]
        int nb2 = u >> 8, up = u & 255, ksd = d >> 6, kp = d & 63;
        size_t off = ((size_t)((((g << 1) + nb2) << 3) + ksd) << 15)
                   + (size_t)((up << 7) + (((kp << 1) ^ ((up & 7) << 4))));
        *(unsigned short*)(w2t + off) = h;
    }
}

// ---------- kernel 3: fused score GEMM, 256x256 tile, BK=64, 8 waves ----------
// Per g: M=32768 (b,t), N=512 (u, 2 blocks of 256), K=512 (8 steps).
// A (values f32) reg-staged -> cvt -> swizzled LDS; B DMA'd from w2t image.
// One vmcnt(0)+barrier per K-step (T3 minimum-2-phase). Epilogue fuses
// tanh + V-dot + u-reduction -> partial scores (summed across nb in finish).
__global__ __launch_bounds__(512, 2) void score_kernel(
    const float* __restrict__ values, const char* __restrict__ w2t,
    const float* __restrict__ qbg, const float* __restrict__ Vvec,
    float* __restrict__ part0, float* __restrict__ part1)
{
    __shared__ char Abuf[2][32768];                 // 256 t-rows x 64 k bf16
    __shared__ char Bbuf[2][32768];                 // 256 u-rows x 64 k bf16
    __shared__ float qbs[256];
    __shared__ float Vs[256];
    __shared__ float spart[4][256];

    const int blk  = blockIdx.x;
    const int g    = blk >> 8;                      // 256 blocks per g
    const int rr   = blk & 255;
    const int mt   = rr >> 1;                       // 128 m-tiles
    const int nb   = rr & 1;                        // u-half
    const int b    = mt >> 2;
    const int t0   = (mt & 3) << 8;                 // 256-row t tile
    const int tid  = threadIdx.x;
    const int lane = tid & 63;
    const int wave = tid >> 6;
    const int wm   = wave >> 2;                     // 2 m-waves
    const int wn   = wave & 3;                      // 4 n-waves
    const int rl   = lane & 31;
    const int hi   = lane >> 5;

    const char* bimg = w2t + ((size_t)((((g << 1) + nb) << 3)) << 15);

    // qb/V slices for this u-half into LDS (one 4B DMA per lane)
    if (wave < 4) {
        const float* qsrc = qbg + (((size_t)(g * NB + b)) << 9) + (nb << 8) + (wave << 6) + lane;
        __builtin_amdgcn_global_load_lds(AS1(qsrc), AS3(&qbs[(wave << 6) + lane]), 4, 0, 0);
    } else {
        const float* vsrc = Vvec + (g << 9) + (nb << 8) + ((wave - 4) << 6) + lane;
        __builtin_amdgcn_global_load_lds(AS1(vsrc), AS3(&Vs[((wave - 4) << 6) + lane]), 4, 0, 0);
    }

    // B: 32 KiB chunk ks -> dst (linear DMA, image pre-swizzled)
    auto stageB = [&](int ks, char* dst) {
        const char* src = bimg + ((size_t)ks << 15) + (wave << 12) + (lane << 4);
        char* d = dst + (wave << 12) + (lane << 4);
        #pragma unroll
        for (int i = 0; i < 4; ++i)
            __builtin_amdgcn_global_load_lds(AS1(src + (i << 10)), AS3(d + (i << 10)), 16, 0, 0);
    };

    // A: thread owns half a row (32 floats) of the 256x64 tile
    const int arow  = tid >> 1;
    const int ahalf = tid & 1;
    const float* aptr = values
        + (((size_t)((g * NB + b) * NT + t0 + arow)) << 9) + (ahalf << 5);
    const int awswz = (arow & 7) << 4;

    float4 av[8];
    auto loadA = [&](int ks) {
        const float4* p4 = (const float4*)(aptr + (ks << 6));
        #pragma unroll
        for (int i = 0; i < 8; ++i) av[i] = p4[i];
    };
    auto writeA = [&](char* dst) {
        char* base = dst + (arow << 7);
        #pragma unroll
        for (int q = 0; q < 4; ++q) {
            uint4 w;
            w.x = cvt_pk_bf16(av[2*q].x,   av[2*q].y);
            w.y = cvt_pk_bf16(av[2*q].z,   av[2*q].w);
            w.z = cvt_pk_bf16(av[2*q+1].x, av[2*q+1].y);
            w.w = cvt_pk_bf16(av[2*q+1].z, av[2*q+1].w);
            *(uint4*)(base + (((ahalf << 6) + (q << 4)) ^ awswz)) = w;
        }
    };

    // fragment addressing (swizzle-aware)
    const int lswz = (rl & 7) << 4;
    int koff[4];
    #pragma unroll
    for (int kf = 0; kf < 4; ++kf) koff[kf] = ((kf << 5) + (hi << 4)) ^ lswz;
    const int abase = (((wm << 7) + rl) << 7);      // (wm*128 + rl) * 128B
    const int bbase = (((wn << 6) + rl) << 7);      // (wn*64  + rl) * 128B

    f32x16 acc[4][2];
    #pragma unroll
    for (int mf = 0; mf < 4; ++mf) {
        acc[mf][0] = (f32x16)(0.0f);
        acc[mf][1] = (f32x16)(0.0f);
    }

    char* Ac = Abuf[0]; char* An = Abuf[1];
    char* Bc = Bbuf[0]; char* Bn = Bbuf[1];

    // prologue: tile 0
    stageB(0, Bc);
    loadA(0);
    asm volatile("s_waitcnt vmcnt(0) lgkmcnt(0)" ::: "memory");
    writeA(Ac);
    asm volatile("s_waitcnt lgkmcnt(0)" ::: "memory");
    __builtin_amdgcn_s_barrier();

    #pragma unroll 1
    for (int ks = 0; ks < 8; ++ks) {
        if (ks < 7) {                               // issue next-tile loads early
            stageB(ks + 1, Bn);
            loadA(ks + 1);
        }
        __builtin_amdgcn_s_setprio(1);
        #pragma unroll
        for (int kf = 0; kf < 4; ++kf) {
            bf16x8 a0 = ld_bf16x8(Ac, abase         + koff[kf]);
            bf16x8 a1 = ld_bf16x8(Ac, abase +  4096 + koff[kf]);
            bf16x8 a2 = ld_bf16x8(Ac, abase +  8192 + koff[kf]);
            bf16x8 a3 = ld_bf16x8(Ac, abase + 12288 + koff[kf]);
            bf16x8 b0 = ld_bf16x8(Bc, bbase         + koff[kf]);
            bf16x8 b1 = ld_bf16x8(Bc, bbase +  4096 + koff[kf]);
            acc[0][0] = __builtin_amdgcn_mfma_f32_32x32x16_bf16(a0, b0, acc[0][0], 0, 0, 0);
            acc[0][1] = __builtin_amdgcn_mfma_f32_32x32x16_bf16(a0, b1, acc[0][1], 0, 0, 0);
            acc[1][0] = __builtin_amdgcn_mfma_f32_32x32x16_bf16(a1, b0, acc[1][0], 0, 0, 0);
            acc[1][1] = __builtin_amdgcn_mfma_f32_32x32x16_bf16(a1, b1, acc[1][1], 0, 0, 0);
            acc[2][0] = __builtin_amdgcn_mfma_f32_32x32x16_bf16(a2, b0, acc[2][0], 0, 0, 0);
            acc[2][1] = __builtin_amdgcn_mfma_f32_32x32x16_bf16(a2, b1, acc[2][1], 0, 0, 0);
            acc[3][0] = __builtin_amdgcn_mfma_f32_32x32x16_bf16(a3, b0, acc[3][0], 0, 0, 0);
            acc[3][1] = __builtin_amdgcn_mfma_f32_32x32x16_bf16(a3, b1, acc[3][1], 0, 0, 0);
        }
        __builtin_amdgcn_s_setprio(0);
        if (ks < 7) {
            asm volatile("s_waitcnt vmcnt(0)" ::: "memory");   // A regs + B DMA landed
            writeA(An);
            asm volatile("s_waitcnt lgkmcnt(0)" ::: "memory"); // ds_writes retired
            __builtin_amdgcn_s_barrier();
            char* t1 = Ac; Ac = An; An = t1;
            char* t2 = Bc; Bc = Bn; Bn = t2;
        }
    }

    // ---- epilogue: tanh + V-dot, reduce over u (32 cols/lane-group) ----
    const float qv0 = qbs[(wn << 6) + rl];
    const float qv1 = qbs[(wn << 6) + 32 + rl];
    const float vv0 = Vs[(wn << 6) + rl];
    const float vv1 = Vs[(wn << 6) + 32 + rl];
    const float CL = 2.8853900817779268f;           // 2*log2(e)
    #pragma unroll
    for (int mf = 0; mf < 4; ++mf) {
        float p[16];
        #pragma unroll
        for (int r2 = 0; r2 < 16; ++r2) {
            float x0 = acc[mf][0][r2] + qv0;
            float x1 = acc[mf][1][r2] + qv1;
            float e0 = exp2f(CL * x0);
            float e1 = exp2f(CL * x1);
            float th0 = 1.f - 2.f * __builtin_amdgcn_rcpf(e0 + 1.f);
            float th1 = 1.f - 2.f * __builtin_amdgcn_rcpf(e1 + 1.f);
            p[r2] = fmaf(th1, vv1, th0 * vv0);
        }
        #pragma unroll
        for (int r2 = 0; r2 < 16; ++r2) {
            float v = p[r2];
            v += __shfl_xor(v, 1);
            v += __shfl_xor(v, 2);
            v += __shfl_xor(v, 4);
            v += __shfl_xor(v, 8);
            v += __shfl_xor(v, 16);
            p[r2] = v;
        }
        if (rl == 0) {
            #pragma unroll
            for (int r2 = 0; r2 < 16; ++r2)
                spart[wn][(wm << 7) + (mf << 5) + (r2 & 3) + 8 * (r2 >> 2) + 4 * hi] = p[r2];
        }
    }
    __syncthreads();
    if (tid < 256) {
        float s = spart[0][tid] + spart[1][tid] + spart[2][tid] + spart[3][tid];
        float* dst = nb ? part1 : part0;
        dst[(((size_t)(g * NB + b)) << 10) + t0 + tid] = s;
    }
}

// ---------- kernel 4: softmax over T + context, 4 d-slices per (g,b) ----------
__global__ __launch_bounds__(256) void finish_kernel(
    const float* __restrict__ part0, const float* __restrict__ part1,
    const float* __restrict__ bV, const float* __restrict__ values,
    float* __restrict__ out_ctx, float* __restrict__ out_w)
{
    __shared__ float sl[NT];
    __shared__ float red[16];
    __shared__ float cred[4][128];
    const int blk   = blockIdx.x;
    const int gb    = blk >> 2;                     // 0..95
    const int slice = blk & 3;                      // d-slice of 128
    const int tid = threadIdx.x;
    const int lane = tid & 63, wid = tid >> 6;
    const float bv = bV[gb >> 5];

    float s[4];
    #pragma unroll
    for (int j = 0; j < 4; ++j) {
        int idx = (int)((size_t)gb * NT) + tid + 256 * j;
        s[j] = part0[idx] + part1[idx] + bv;
    }

    float m = fmaxf(fmaxf(s[0], s[1]), fmaxf(s[2], s[3]));
    #pragma unroll
    for (int mask = 32; mask; mask >>= 1) m = fmaxf(m, __shfl_xor(m, mask));
    if (lane == 0) red[wid] = m;
    __syncthreads();
    const float gm = fmaxf(fmaxf(red[0], red[1]), fmaxf(red[2], red[3]));

    float e[4], ps = 0.f;
    #pragma unroll
    for (int j = 0; j < 4; ++j) { e[j] = __expf(s[j] - gm); ps += e[j]; }
    #pragma unroll
    for (int mask = 32; mask; mask >>= 1) ps += __shfl_xor(ps, mask);
    if (lane == 0) red[8 + wid] = ps;
    __syncthreads();
    const float inv = 1.f / (red[8] + red[9] + red[10] + red[11]);

    #pragma unroll
    for (int j = 0; j < 4; ++j) {
        float w = e[j] * inv;
        sl[tid + 256 * j] = w;
        if (slice == 0) out_w[(size_t)gb * NT + tid + 256 * j] = w;
    }
    __syncthreads();

    const int dp = tid & 63;
    const int tg = tid >> 6;
    const float* vbase = values + (size_t)gb * NT * ND + slice * 128 + dp * 2;
    float ax = 0.f, ay = 0.f;
    #pragma unroll 4
    for (int t = tg; t < NT; t += 4) {
        float2 v = *(const float2*)(vbase + (size_t)t * ND);
        float w = sl[t];
        ax = fmaf(w, v.x, ax);
        ay = fmaf(w, v.y, ay);
    }
    cred[tg][dp * 2]     = ax;
    cred[tg][dp * 2 + 1] = ay;
    __syncthreads();
    if (tid < 128) {
        float r = cred[0][tid] + cred[1][tid] + cred[2][tid] + cred[3][tid];
        out_ctx[(size_t)gb * ND + slice * 128 + tid] = r;
    }
}

extern "C" void kernel_launch(void* const* d_in, const int* in_sizes, int n_in,
                              void* d_out, int out_size, void* d_ws, size_t ws_size,
                              hipStream_t stream)
{
    (void)in_sizes; (void)n_in; (void)out_size; (void)ws_size;
    const float* query  = (const float*)d_in[0];
    const float* values = (const float*)d_in[1];
    const float* W1     = (const float*)d_in[2];
    const float* b1     = (const float*)d_in[3];
    const float* W2     = (const float*)d_in[4];
    const float* b2     = (const float*)d_in[5];
    const float* Vv     = (const float*)d_in[6];
    const float* bV     = (const float*)d_in[7];

    float* out_ctx = (float*)d_out;
    float* out_w   = out_ctx + (size_t)NG * NB * ND;

    // ws: qb (192 KiB) | part0/part1 (2 x 384 KiB) | w2t image (1.5 MiB)
    float* qb    = (float*)d_ws;
    float* part0 = qb + (size_t)NG * NB * NU;
    float* part1 = part0 + (size_t)NG * NB * NT;
    char*  w2t   = (char*)(part1 + (size_t)NG * NB * NT);

    prep_qb_kernel <<<NG * 8,   256, 0, stream>>>(query, W1, b1, b2, qb);
    prep_w2t_kernel<<<NG * 64,  256, 0, stream>>>(W2, w2t);
    score_kernel   <<<NG * 256, 512, 0, stream>>>(values, w2t, qb, Vv, part0, part1);
    finish_kernel  <<<NG * NB * 4, 256, 0, stream>>>(part0, part1, bV, values, out_ctx, out_w);
}